// Round 4
// baseline (200.362 us; speedup 1.0000x reference)
//
#include <hip/hip_runtime.h>
#include <cstdint>
#include <cstddef>

typedef __attribute__((ext_vector_type(8))) short bf16x8;
typedef __attribute__((ext_vector_type(4))) float f32x4;
typedef __attribute__((ext_vector_type(8))) unsigned short ushort8;
typedef __attribute__((ext_vector_type(4))) unsigned short ushort4v;

#define B_SZ   512
#define D1_IN  40
#define T_DIM  1024
#define D1_OUT 120
#define D2_OUT 64
#define OUT0_SZ (B_SZ * D1_OUT * D2_OUT) // 3932160

// per-bn bitmask of nonzero 32-wide k-steps of W (general sparsity skip)
__device__ unsigned int g_wmask[8];

// ---- helpers ----
__device__ __forceinline__ unsigned short f2bf(float f) {
    unsigned int u = __float_as_uint(f);
    u += 0x7FFFu + ((u >> 16) & 1u);   // RNE
    return (unsigned short)(u >> 16);
}
__device__ __forceinline__ float bf2f(unsigned short h) {
    return __uint_as_float(((unsigned int)h) << 16);
}
__device__ __forceinline__ void gld16v(const void* g, void* l) {
    __builtin_amdgcn_global_load_lds(
        (const __attribute__((address_space(1))) unsigned int*)g,
        (__attribute__((address_space(3))) unsigned int*)l, 16, 0, 0);
}

// ---- merged small prep: W2 transpose (blocks 0..63), wmask (64..71), w1pad (72) ----
__global__ __launch_bounds__(256) void k_prep_small(const float* __restrict__ W1,
                                                    const float* __restrict__ W,
                                                    const float* __restrict__ W2,
                                                    unsigned short* __restrict__ w2t,
                                                    unsigned short* __restrict__ w1p) {
    int blk = blockIdx.x, tid = threadIdx.x;
    if (blk < 64) {
        // transpose W2 (1024x64 fp32) -> w2t (64x1024 bf16)
        __shared__ float tile[32][33];
        int c0 = (blk & 1) * 32, r0 = (blk >> 1) * 32;
        int tx = tid & 31, ty = tid >> 5;
        #pragma unroll
        for (int i = 0; i < 4; i++)
            tile[ty + i * 8][tx] = W2[(size_t)(r0 + ty + i * 8) * D2_OUT + c0 + tx];
        __syncthreads();
        #pragma unroll
        for (int i = 0; i < 4; i++)
            w2t[(size_t)(c0 + ty + i * 8) * T_DIM + r0 + tx] = f2bf(tile[tx][ty + i * 8]);
    } else if (blk < 72) {
        // wmask: panel bn = blk-64 of W
        __shared__ unsigned int sm[256];
        int bn = blk - 64;
        int rbase = tid >> 5, c0 = (tid & 31) * 4;
        unsigned int m = 0;
        for (int ks = 0; ks < 32; ks++) {
            bool nz = false;
            #pragma unroll
            for (int i = 0; i < 4; i++) {
                int r = ks * 32 + rbase + i * 8;
                float4 v = *(const float4*)(W + (size_t)r * T_DIM + bn * 128 + c0);
                nz |= (v.x != 0.f) | (v.y != 0.f) | (v.z != 0.f) | (v.w != 0.f);
            }
            if (nz) m |= (1u << ks);
        }
        sm[tid] = m;
        __syncthreads();
        if (tid == 0) {
            unsigned int acc = 0;
            for (int i = 0; i < 256; i++) acc |= sm[i];
            g_wmask[bn] = acc;
        }
    } else {
        // w1pad: W1 (120x40) -> 128x64 bf16 zero-padded
        for (int i = tid; i < 128 * 64; i += 256) {
            int o = i >> 6, f = i & 63;
            w1p[i] = (o < D1_OUT && f < D1_IN) ? f2bf(W1[o * D1_IN + f]) : (unsigned short)0;
        }
    }
}

// ---- transpose W (1024x1024 fp32) -> wt (1024x1024 bf16) ----
__global__ __launch_bounds__(256) void k_transpose_w(const float* __restrict__ src,
                                                     unsigned short* __restrict__ dst) {
    __shared__ float tile[32][33];
    int c0 = blockIdx.x * 32, r0 = blockIdx.y * 32;
    int tx = threadIdx.x & 31, ty = threadIdx.x >> 5;
    #pragma unroll
    for (int i = 0; i < 4; i++)
        tile[ty + i * 8][tx] = src[(size_t)(r0 + ty + i * 8) * T_DIM + c0 + tx];
    __syncthreads();
    #pragma unroll
    for (int i = 0; i < 4; i++)
        dst[(size_t)(c0 + ty + i * 8) * T_DIM + r0 + tx] = f2bf(tile[tx][ty + i * 8]);
}

// ---- GEMM1: E(bf16) = x(20480x1024 fp32, cvt on stage) @ Wt^T, masked k-steps ----
__global__ __launch_bounds__(256) void k_gemm1(const float* __restrict__ x,
                                               const unsigned short* __restrict__ wt,
                                               unsigned short* __restrict__ E) {
    __shared__ unsigned short As[128 * 40];   // stride 40 (pad) bf16
    __shared__ unsigned short Bs[128 * 32];
    int bm = blockIdx.x >> 3, bn = blockIdx.x & 7;   // 160 x 8
    int tid = threadIdx.x, l = tid & 63, w = tid >> 6;
    int wr = w >> 1, wc = w & 1;
    int rr = l & 15, q = l >> 4;
    unsigned int mask = g_wmask[bn];
    f32x4 acc[4][4] = {};
    for (int ks = 0; ks < 32; ks++) {
        if (!((mask >> ks) & 1u)) continue;
        int k0 = ks * 32;
        __syncthreads();
        // A-panel: x fp32 -> bf16 LDS (reg-staged, padded stride)
        #pragma unroll
        for (int i = 0; i < 4; i++) {
            int idx = i * 256 + tid;
            int r = idx >> 3, c4 = idx & 7;
            float4 v = *(const float4*)(x + (size_t)(bm * 128 + r) * T_DIM + k0 + c4 * 4);
            ushort4v o;
            o.x = f2bf(v.x); o.y = f2bf(v.y); o.z = f2bf(v.z); o.w = f2bf(v.w);
            *(ushort4v*)&As[r * 40 + c4 * 4] = o;
        }
        // B-panel: wt bf16 direct-to-LDS
        #pragma unroll
        for (int i = 0; i < 2; i++) {
            int ch = i * 256 + tid;
            int r = ch >> 2, c = ch & 3;
            gld16v(wt + (size_t)(bn * 128 + r) * T_DIM + k0 + c * 8, &Bs[ch * 8]);
        }
        __syncthreads();
        bf16x8 a[4], b[4];
        #pragma unroll
        for (int m = 0; m < 4; m++) a[m] = *(const bf16x8*)&As[(wr * 64 + m * 16 + rr) * 40 + q * 8];
        #pragma unroll
        for (int n = 0; n < 4; n++) b[n] = *(const bf16x8*)&Bs[(wc * 64 + n * 16 + rr) * 32 + q * 8];
        #pragma unroll
        for (int m = 0; m < 4; m++)
            #pragma unroll
            for (int n = 0; n < 4; n++)
                acc[m][n] = __builtin_amdgcn_mfma_f32_16x16x32_bf16(a[m], b[n], acc[m][n], 0, 0, 0);
    }
    #pragma unroll
    for (int m = 0; m < 4; m++)
        #pragma unroll
        for (int n = 0; n < 4; n++)
            #pragma unroll
            for (int j = 0; j < 4; j++) {
                int row = wr * 64 + m * 16 + q * 4 + j;
                int col = wc * 64 + n * 16 + rr;
                E[(size_t)(bm * 128 + row) * T_DIM + bn * 128 + col] = f2bf(acc[m][n][j]);
            }
}

// ---- softmax per row: A(fp32, to d_out) = softmax(E bf16) ----
__global__ __launch_bounds__(256) void k_softmax(const unsigned short* __restrict__ E,
                                                 float* __restrict__ A) {
    int row = blockIdx.x * 4 + (threadIdx.x >> 6);
    int l = threadIdx.x & 63;
    const ushort8* pe = (const ushort8*)(E + (size_t)row * T_DIM + l * 16);
    ushort8 u0 = pe[0], u1 = pe[1];
    float v[16];
    #pragma unroll
    for (int j = 0; j < 8; j++) { v[j] = bf2f(u0[j]); v[8 + j] = bf2f(u1[j]); }
    float m = v[0];
    #pragma unroll
    for (int j = 1; j < 16; j++) m = fmaxf(m, v[j]);
    for (int off = 32; off > 0; off >>= 1) m = fmaxf(m, __shfl_xor(m, off));
    float s = 0.f;
    #pragma unroll
    for (int j = 0; j < 16; j++) { v[j] = __expf(v[j] - m); s += v[j]; }
    for (int off = 32; off > 0; off >>= 1) s += __shfl_xor(s, off);
    float inv = 1.f / s;
    float4* pa = (float4*)(A + (size_t)row * T_DIM + l * 16);
    #pragma unroll
    for (int j = 0; j < 4; j++) {
        float4 o;
        o.x = v[j * 4 + 0] * inv; o.y = v[j * 4 + 1] * inv;
        o.z = v[j * 4 + 2] * inv; o.w = v[j * 4 + 3] * inv;
        pa[j] = o;
    }
}

// ---- prepxT: x (fp32 [b][f][t]) -> xbT (bf16 [b][t][64], f-padded, block-swizzled) ----
// storage: row t holds element f at position ((f>>3) ^ (t&7))*8 + (f&7)
__global__ __launch_bounds__(256) void k_prepxT(const float* __restrict__ x,
                                                unsigned short* __restrict__ xbT) {
    __shared__ unsigned short tl[64 * 72];
    int b = blockIdx.x >> 4, tc = blockIdx.x & 15, t0 = tc * 64;
    int tid = threadIdx.x;
    for (int i = tid; i < 64 * 72; i += 256) tl[i] = 0;
    __syncthreads();
    for (int i = tid; i < 640; i += 256) {
        int f = i >> 4, t4 = (i & 15) * 4;
        float4 v = *(const float4*)(x + ((size_t)b * D1_IN + f) * T_DIM + t0 + t4);
        int blk = f >> 3, fl = f & 7;
        const float* vp = &v.x;
        #pragma unroll
        for (int j = 0; j < 4; j++) {
            int t = t4 + j;
            tl[t * 72 + (((blk ^ (t & 7)) << 3) + fl)] = f2bf(vp[j]);
        }
    }
    __syncthreads();
    int r = tid >> 2, p = tid & 3;
    ushort8 u0 = *(const ushort8*)&tl[r * 72 + p * 16];
    ushort8 u1 = *(const ushort8*)&tl[r * 72 + p * 16 + 8];
    size_t orow = ((size_t)b * T_DIM + t0 + r) * 64;
    *(ushort8*)(xbT + orow + p * 16) = u0;
    *(ushort8*)(xbT + orow + p * 16 + 8) = u1;
}

// ---- fused: X_bar^T = x^T@W1^T via MFMA (D=[t][o]), gate in-reg, X_tilde->LDS b64,
//      out = X_tilde@W2 + B, relu. 2-phase double-buffered, gate prefetched in regs.
__global__ __launch_bounds__(512) void k_fused(const unsigned short* __restrict__ xbT,
                                               const unsigned short* __restrict__ w1p,
                                               const float* __restrict__ A,
                                               const unsigned short* __restrict__ w2t,
                                               const float* __restrict__ Bias,
                                               const float* __restrict__ lamp,
                                               float* __restrict__ out) {
    __shared__ unsigned short xst[2][64 * 64];  // swizzled x chunk [t][f-blocks]
    __shared__ unsigned short xtl[128 * 72];    // X_tilde [o][t], stride 72
    int b = blockIdx.x;
    int tid = threadIdx.x, l = tid & 63, w = tid >> 6;   // 8 waves, 16 o-rows each
    int rr = l & 15, q = l >> 4;
    float lam = fminf(fmaxf(lamp[0], 0.f), 1.f), oml = 1.f - lam;
    // W1 B-fragments: col=lane&15 -> o = w*16+rr, k = f = q*8+j
    bf16x8 aw[2];
    #pragma unroll
    for (int ks = 0; ks < 2; ks++)
        aw[ks] = *(const bf16x8*)(w1p + (w * 16 + rr) * 64 + ks * 32 + q * 8);
    int og = w * 16 + rr;              // lane's fixed o (strip row)
    int am = og % D1_IN;               // gather row of A for the gate
    int rowv[4];
    #pragma unroll
    for (int j = 0; j < 4; j++) rowv[j] = w * 16 + q * 4 + j;   // epilogue o (D2 rows)
    f32x4 acc2[4] = {};
    const unsigned short* xTb = xbT + (size_t)b * T_DIM * 64;
    const float* Ag = A + ((size_t)b * D1_IN + am) * T_DIM;     // per-lane gate row

    // stage x chunk t0 into buffer buf: wave w stages rows w*8..w*8+7 (lane-linear)
    auto STAGE = [&](int buf, int t0) {
        gld16v(xTb + ((size_t)(t0 + w * 8 + (l >> 3))) * 64 + (l & 7) * 8,
               &xst[buf][w * 8 * 64]);
    };

    float4 gv[4], gn[4];
    STAGE(0, 0);
    #pragma unroll
    for (int ni = 0; ni < 4; ni++) gv[ni] = *(const float4*)(Ag + ni * 16 + q * 4);
    __syncthreads();
    for (int tc = 0; tc < 16; tc++) {
        int cur = tc & 1, t0 = tc * 64;
        if (tc < 15) {
            STAGE(cur ^ 1, t0 + 64);
            // prefetch next chunk's gate (registers; consumed next iteration)
            #pragma unroll
            for (int ni = 0; ni < 4; ni++)
                gn[ni] = *(const float4*)(Ag + t0 + 64 + ni * 16 + q * 4);
        }
        // w2 B-fragments to regs, issued early (consumed at end of chunk)
        bf16x8 b2[2][4];
        #pragma unroll
        for (int ks2 = 0; ks2 < 2; ks2++)
            #pragma unroll
            for (int ni = 0; ni < 4; ni++)
                b2[ks2][ni] = *(const bf16x8*)(w2t + (size_t)(ni * 16 + rr) * T_DIM + t0 + ks2 * 32 + q * 8);
        // X_bar^T via MFMA: D[t][o], lane holds t = ni*16 + q*4+j at fixed o = og
        f32x4 acc1[4] = {};
        #pragma unroll
        for (int ni = 0; ni < 4; ni++)
            #pragma unroll
            for (int ks = 0; ks < 2; ks++) {
                bf16x8 bx = *(const bf16x8*)&xst[cur][(ni * 16 + rr) * 64 + (((ks * 4 + q) ^ (rr & 7)) << 3)];
                acc1[ni] = __builtin_amdgcn_mfma_f32_16x16x32_bf16(bx, aw[ks], acc1[ni], 0, 0, 0);
            }
        // gate (regs) + pack 4 consecutive t as bf16 pairs -> one ds_write_b64 per ni
        #pragma unroll
        for (int ni = 0; ni < 4; ni++) {
            float e0 = acc1[ni][0] * (lam * gv[ni].x + oml);
            float e1 = acc1[ni][1] * (lam * gv[ni].y + oml);
            float e2 = acc1[ni][2] * (lam * gv[ni].z + oml);
            float e3 = acc1[ni][3] * (lam * gv[ni].w + oml);
            uint2 pk;
            pk.x = (unsigned int)f2bf(e0) | ((unsigned int)f2bf(e1) << 16);
            pk.y = (unsigned int)f2bf(e2) | ((unsigned int)f2bf(e3) << 16);
            *(uint2*)&xtl[og * 72 + ni * 16 + q * 4] = pk;
        }
        // GEMM2: A-frag row = og (same-wave RAW on xtl; DS in-order + compiler lgkm)
        #pragma unroll
        for (int ks2 = 0; ks2 < 2; ks2++) {
            bf16x8 a2 = *(const bf16x8*)&xtl[og * 72 + ks2 * 32 + q * 8];
            #pragma unroll
            for (int ni = 0; ni < 4; ni++)
                acc2[ni] = __builtin_amdgcn_mfma_f32_16x16x32_bf16(a2, b2[ks2][ni], acc2[ni], 0, 0, 0);
        }
        #pragma unroll
        for (int ni = 0; ni < 4; ni++) gv[ni] = gn[ni];
        __syncthreads();   // drains staged gld16 (vmcnt) + protects xst buffers
    }
    #pragma unroll
    for (int ni = 0; ni < 4; ni++)
        #pragma unroll
        for (int j = 0; j < 4; j++) {
            int row = rowv[j];
            if (row < D1_OUT) {
                int col = ni * 16 + rr;
                float v = acc2[ni][j] + Bias[row * D2_OUT + col];
                out[((size_t)b * D1_OUT + row) * D2_OUT + col] = fmaxf(v, 0.f);
            }
        }
}

extern "C" void kernel_launch(void* const* d_in, const int* in_sizes, int n_in,
                              void* d_out, int out_size, void* d_ws, size_t ws_size,
                              hipStream_t stream) {
    const float* x    = (const float*)d_in[0];
    const float* W1   = (const float*)d_in[1];
    const float* W    = (const float*)d_in[2];
    const float* W2   = (const float*)d_in[3];
    const float* Bias = (const float*)d_in[4];
    const float* lam  = (const float*)d_in[5];
    float* out = (float*)d_out;
    float* A   = out + OUT0_SZ;                    // second output region

    char* ws = (char*)d_ws;
    // region 0 (64 MB): E (first 40 MB) then reused as xbT after softmax
    unsigned short* E   = (unsigned short*)(ws);
    unsigned short* xbT = (unsigned short*)(ws);
    unsigned short* wt  = (unsigned short*)(ws + 67108864);   // 2 MB
    unsigned short* w2t = (unsigned short*)(ws + 69206016);   // 128 KB
    unsigned short* w1p = (unsigned short*)(ws + 69337088);   // 16 KB  (total ~69.4 MB)

    hipLaunchKernelGGL(k_prep_small, dim3(73), dim3(256), 0, stream, W1, W, W2, w2t, w1p);
    hipLaunchKernelGGL(k_transpose_w, dim3(32, 32), dim3(256), 0, stream, W, wt);
    hipLaunchKernelGGL(k_gemm1, dim3(1280), dim3(256), 0, stream, x, wt, E);
    hipLaunchKernelGGL(k_softmax, dim3(5120), dim3(256), 0, stream, E, A);
    hipLaunchKernelGGL(k_prepxT, dim3(8192), dim3(256), 0, stream, x, xbT);
    hipLaunchKernelGGL(k_fused, dim3(512), dim3(512), 0, stream, xbT, w1p, A, w2t, Bias, lam, out);
}

// Round 5
// 144.027 us; speedup vs baseline: 1.3911x; 1.3911x over previous
//
#include <hip/hip_runtime.h>
#include <cstdint>
#include <cstddef>

typedef __attribute__((ext_vector_type(8))) short bf16x8;
typedef __attribute__((ext_vector_type(4))) float f32x4;
typedef __attribute__((ext_vector_type(8))) unsigned short ushort8;
typedef __attribute__((ext_vector_type(4))) unsigned short ushort4v;

#define B_SZ   512
#define D1_IN  40
#define T_DIM  1024
#define D1_OUT 120
#define D2_OUT 64
#define OUT0_SZ (B_SZ * D1_OUT * D2_OUT) // 3932160

// per-bn bitmask of nonzero 32-wide k-steps of W (general sparsity skip)
__device__ unsigned int g_wmask[8];

// ---- helpers ----
__device__ __forceinline__ unsigned short f2bf(float f) {
    unsigned int u = __float_as_uint(f);
    u += 0x7FFFu + ((u >> 16) & 1u);   // RNE
    return (unsigned short)(u >> 16);
}
__device__ __forceinline__ float bf2f(unsigned short h) {
    return __uint_as_float(((unsigned int)h) << 16);
}
__device__ __forceinline__ void gld16v(const void* g, void* l) {
    __builtin_amdgcn_global_load_lds(
        (const __attribute__((address_space(1))) unsigned int*)g,
        (__attribute__((address_space(3))) unsigned int*)l, 16, 0, 0);
}

// ---- merged small prep: W2 swizzled re-layout (blocks 0..63), wmask (64..71), w1pad (72) ----
// w2g layout: [tc][s][blk^ (s&7)][8]  (chunk-major so a 64-t chunk is one contiguous 8KB)
__global__ __launch_bounds__(256) void k_prep_small(const float* __restrict__ W1,
                                                    const float* __restrict__ W,
                                                    const float* __restrict__ W2,
                                                    unsigned short* __restrict__ w2g,
                                                    unsigned short* __restrict__ w1p) {
    int blk = blockIdx.x, tid = threadIdx.x;
    if (blk < 64) {
        // transpose W2 (1024x64 fp32) tile -> w2g (bf16, swizzled chunk-major)
        __shared__ float tile[32][33];
        int c0 = (blk & 1) * 32, r0 = (blk >> 1) * 32;
        int tx = tid & 31, ty = tid >> 5;
        #pragma unroll
        for (int i = 0; i < 4; i++)
            tile[ty + i * 8][tx] = W2[(size_t)(r0 + ty + i * 8) * D2_OUT + c0 + tx];
        __syncthreads();
        #pragma unroll
        for (int i = 0; i < 4; i++) {
            int s = c0 + ty + i * 8;      // 0..63
            int t = r0 + tx;              // 0..1023
            size_t idx = ((size_t)(t >> 6) * 64 + s) * 64
                       + ((((t >> 3) & 7) ^ (s & 7)) << 3) + (t & 7);
            w2g[idx] = f2bf(tile[tx][ty + i * 8]);
        }
    } else if (blk < 72) {
        // wmask: panel bn = blk-64 of W
        __shared__ unsigned int sm[256];
        int bn = blk - 64;
        int rbase = tid >> 5, c0 = (tid & 31) * 4;
        unsigned int m = 0;
        for (int ks = 0; ks < 32; ks++) {
            bool nz = false;
            #pragma unroll
            for (int i = 0; i < 4; i++) {
                int r = ks * 32 + rbase + i * 8;
                float4 v = *(const float4*)(W + (size_t)r * T_DIM + bn * 128 + c0);
                nz |= (v.x != 0.f) | (v.y != 0.f) | (v.z != 0.f) | (v.w != 0.f);
            }
            if (nz) m |= (1u << ks);
        }
        sm[tid] = m;
        __syncthreads();
        if (tid == 0) {
            unsigned int acc = 0;
            for (int i = 0; i < 256; i++) acc |= sm[i];
            g_wmask[bn] = acc;
        }
    } else {
        // w1pad: W1 (120x40) -> 128x64 bf16 zero-padded
        for (int i = tid; i < 128 * 64; i += 256) {
            int o = i >> 6, f = i & 63;
            w1p[i] = (o < D1_OUT && f < D1_IN) ? f2bf(W1[o * D1_IN + f]) : (unsigned short)0;
        }
    }
}

// ---- transpose W (1024x1024 fp32) -> wt (1024x1024 bf16) ----
__global__ __launch_bounds__(256) void k_transpose_w(const float* __restrict__ src,
                                                     unsigned short* __restrict__ dst) {
    __shared__ float tile[32][33];
    int c0 = blockIdx.x * 32, r0 = blockIdx.y * 32;
    int tx = threadIdx.x & 31, ty = threadIdx.x >> 5;
    #pragma unroll
    for (int i = 0; i < 4; i++)
        tile[ty + i * 8][tx] = src[(size_t)(r0 + ty + i * 8) * T_DIM + c0 + tx];
    __syncthreads();
    #pragma unroll
    for (int i = 0; i < 4; i++)
        dst[(size_t)(c0 + ty + i * 8) * T_DIM + r0 + tx] = f2bf(tile[tx][ty + i * 8]);
}

// ---- GEMM1: E(bf16) = x(20480x1024 fp32, cvt on stage) @ Wt^T, masked k-steps ----
__global__ __launch_bounds__(256) void k_gemm1(const float* __restrict__ x,
                                               const unsigned short* __restrict__ wt,
                                               unsigned short* __restrict__ E) {
    __shared__ unsigned short As[128 * 40];   // stride 40 (pad) bf16
    __shared__ unsigned short Bs[128 * 32];
    int bm = blockIdx.x >> 3, bn = blockIdx.x & 7;   // 160 x 8
    int tid = threadIdx.x, l = tid & 63, w = tid >> 6;
    int wr = w >> 1, wc = w & 1;
    int rr = l & 15, q = l >> 4;
    unsigned int mask = g_wmask[bn];
    f32x4 acc[4][4] = {};
    for (int ks = 0; ks < 32; ks++) {
        if (!((mask >> ks) & 1u)) continue;
        int k0 = ks * 32;
        __syncthreads();
        // A-panel: x fp32 -> bf16 LDS (reg-staged, padded stride)
        #pragma unroll
        for (int i = 0; i < 4; i++) {
            int idx = i * 256 + tid;
            int r = idx >> 3, c4 = idx & 7;
            float4 v = *(const float4*)(x + (size_t)(bm * 128 + r) * T_DIM + k0 + c4 * 4);
            ushort4v o;
            o.x = f2bf(v.x); o.y = f2bf(v.y); o.z = f2bf(v.z); o.w = f2bf(v.w);
            *(ushort4v*)&As[r * 40 + c4 * 4] = o;
        }
        // B-panel: wt bf16 direct-to-LDS
        #pragma unroll
        for (int i = 0; i < 2; i++) {
            int ch = i * 256 + tid;
            int r = ch >> 2, c = ch & 3;
            gld16v(wt + (size_t)(bn * 128 + r) * T_DIM + k0 + c * 8, &Bs[ch * 8]);
        }
        __syncthreads();
        bf16x8 a[4], b[4];
        #pragma unroll
        for (int m = 0; m < 4; m++) a[m] = *(const bf16x8*)&As[(wr * 64 + m * 16 + rr) * 40 + q * 8];
        #pragma unroll
        for (int n = 0; n < 4; n++) b[n] = *(const bf16x8*)&Bs[(wc * 64 + n * 16 + rr) * 32 + q * 8];
        #pragma unroll
        for (int m = 0; m < 4; m++)
            #pragma unroll
            for (int n = 0; n < 4; n++)
                acc[m][n] = __builtin_amdgcn_mfma_f32_16x16x32_bf16(a[m], b[n], acc[m][n], 0, 0, 0);
    }
    #pragma unroll
    for (int m = 0; m < 4; m++)
        #pragma unroll
        for (int n = 0; n < 4; n++)
            #pragma unroll
            for (int j = 0; j < 4; j++) {
                int row = wr * 64 + m * 16 + q * 4 + j;
                int col = wc * 64 + n * 16 + rr;
                E[(size_t)(bm * 128 + row) * T_DIM + bn * 128 + col] = f2bf(acc[m][n][j]);
            }
}

// ---- softmax per row: A(fp32, to d_out) = softmax(E bf16) ----
__global__ __launch_bounds__(256) void k_softmax(const unsigned short* __restrict__ E,
                                                 float* __restrict__ A) {
    int row = blockIdx.x * 4 + (threadIdx.x >> 6);
    int l = threadIdx.x & 63;
    const ushort8* pe = (const ushort8*)(E + (size_t)row * T_DIM + l * 16);
    ushort8 u0 = pe[0], u1 = pe[1];
    float v[16];
    #pragma unroll
    for (int j = 0; j < 8; j++) { v[j] = bf2f(u0[j]); v[8 + j] = bf2f(u1[j]); }
    float m = v[0];
    #pragma unroll
    for (int j = 1; j < 16; j++) m = fmaxf(m, v[j]);
    for (int off = 32; off > 0; off >>= 1) m = fmaxf(m, __shfl_xor(m, off));
    float s = 0.f;
    #pragma unroll
    for (int j = 0; j < 16; j++) { v[j] = __expf(v[j] - m); s += v[j]; }
    for (int off = 32; off > 0; off >>= 1) s += __shfl_xor(s, off);
    float inv = 1.f / s;
    float4* pa = (float4*)(A + (size_t)row * T_DIM + l * 16);
    #pragma unroll
    for (int j = 0; j < 4; j++) {
        float4 o;
        o.x = v[j * 4 + 0] * inv; o.y = v[j * 4 + 1] * inv;
        o.z = v[j * 4 + 2] * inv; o.w = v[j * 4 + 3] * inv;
        pa[j] = o;
    }
}

// ---- prepxT: x (fp32 [b][f][t]) -> xbT (bf16 [b][t][64], f-padded, block-swizzled) ----
// storage: row t holds element f at position ((f>>3) ^ (t&7))*8 + (f&7)
__global__ __launch_bounds__(256) void k_prepxT(const float* __restrict__ x,
                                                unsigned short* __restrict__ xbT) {
    __shared__ unsigned short tl[64 * 72];
    int b = blockIdx.x >> 4, tc = blockIdx.x & 15, t0 = tc * 64;
    int tid = threadIdx.x;
    for (int i = tid; i < 64 * 72; i += 256) tl[i] = 0;
    __syncthreads();
    for (int i = tid; i < 640; i += 256) {
        int f = i >> 4, t4 = (i & 15) * 4;
        float4 v = *(const float4*)(x + ((size_t)b * D1_IN + f) * T_DIM + t0 + t4);
        int blk = f >> 3, fl = f & 7;
        const float* vp = &v.x;
        #pragma unroll
        for (int j = 0; j < 4; j++) {
            int t = t4 + j;
            tl[t * 72 + (((blk ^ (t & 7)) << 3) + fl)] = f2bf(vp[j]);
        }
    }
    __syncthreads();
    int r = tid >> 2, p = tid & 3;
    ushort8 u0 = *(const ushort8*)&tl[r * 72 + p * 16];
    ushort8 u1 = *(const ushort8*)&tl[r * 72 + p * 16 + 8];
    size_t orow = ((size_t)b * T_DIM + t0 + r) * 64;
    *(ushort8*)(xbT + orow + p * 16) = u0;
    *(ushort8*)(xbT + orow + p * 16 + 8) = u1;
}

// ---- fused: X_bar^T = x^T@W1^T via MFMA (D=[t][o]), gate from LDS, X_tilde->LDS b64,
//      out = X_tilde@W2 + B, relu. 2-phase double-buffered; ALL global loads coalesced
//      via global_load_lds (xst, w2s, gst). ----
__global__ __launch_bounds__(512) void k_fused(const unsigned short* __restrict__ xbT,
                                               const unsigned short* __restrict__ w1p,
                                               const float* __restrict__ A,
                                               const unsigned short* __restrict__ w2g,
                                               const float* __restrict__ Bias,
                                               const float* __restrict__ lamp,
                                               float* __restrict__ out) {
    __shared__ unsigned short xst[2][64 * 64];  // swizzled x chunk [t][f-blocks]   16KB
    __shared__ unsigned short w2s[2][64 * 64];  // swizzled w2 chunk [s][t-blocks]  16KB
    __shared__ float gst[2][40 * 64];           // A chunk [f][t] fp32              20KB
    __shared__ unsigned short xtl[128 * 72];    // X_tilde [o][t], stride 72        18KB
    int b = blockIdx.x;
    int tid = threadIdx.x, l = tid & 63, w = tid >> 6;   // 8 waves, 16 o-rows each
    int rr = l & 15, q = l >> 4;
    float lam = fminf(fmaxf(lamp[0], 0.f), 1.f), oml = 1.f - lam;
    // W1 B-fragments: col=lane&15 -> o = w*16+rr, k = f = q*8+j
    bf16x8 aw[2];
    #pragma unroll
    for (int ks = 0; ks < 2; ks++)
        aw[ks] = *(const bf16x8*)(w1p + (w * 16 + rr) * 64 + ks * 32 + q * 8);
    int og = w * 16 + rr;              // lane's fixed o (strip row)
    int am = og % D1_IN;               // gate row of A
    int rowv[4];
    #pragma unroll
    for (int j = 0; j < 4; j++) rowv[j] = w * 16 + q * 4 + j;   // epilogue o rows
    f32x4 acc2[4] = {};
    const unsigned short* xTb = xbT + (size_t)b * T_DIM * 64;
    const float* Ab = A + (size_t)b * D1_IN * T_DIM;

    // stage chunk tc into buffer buf (all coalesced global_load_lds)
    auto STAGE = [&](int buf, int tc) {
        int t0 = tc * 64;
        // x chunk: wave w stages t-rows w*8..w*8+7 (contiguous 1KB)
        gld16v(xTb + (size_t)(t0 + w * 8 + (l >> 3)) * 64 + (l & 7) * 8,
               &xst[buf][w * 512]);
        // w2 chunk: contiguous 1KB per wave (chunk-major global layout)
        gld16v(w2g + (size_t)tc * 4096 + w * 512 + l * 8,
               &w2s[buf][w * 512]);
        // gate: A rows, fp32; waves 0..7 rows 4w..4w+3, waves 0..1 rows 32..39
        gld16v(Ab + (size_t)(w * 4 + (l >> 4)) * T_DIM + t0 + (l & 15) * 4,
               &gst[buf][w * 256]);
        if (w < 2)
            gld16v(Ab + (size_t)(32 + w * 4 + (l >> 4)) * T_DIM + t0 + (l & 15) * 4,
                   &gst[buf][(32 + w * 4) * 64]);
    };

    STAGE(0, 0);
    __syncthreads();   // drains vmcnt(0) (compiler-inserted before barrier)
    for (int tc = 0; tc < 16; tc++) {
        int cur = tc & 1;
        if (tc < 15) STAGE(cur ^ 1, tc + 1);
        // X_bar^T via MFMA: D[t][o], lane holds t = ni*16 + q*4+j at fixed o = og
        f32x4 acc1[4] = {};
        #pragma unroll
        for (int ni = 0; ni < 4; ni++)
            #pragma unroll
            for (int ks = 0; ks < 2; ks++) {
                bf16x8 bx = *(const bf16x8*)&xst[cur][(ni * 16 + rr) * 64 + (((ks * 4 + q) ^ (rr & 7)) << 3)];
                acc1[ni] = __builtin_amdgcn_mfma_f32_16x16x32_bf16(bx, aw[ks], acc1[ni], 0, 0, 0);
            }
        // gate (LDS, lane-fixed row am) + pack -> one ds_write_b64 per ni
        const float* gr = &gst[cur][am * 64];
        #pragma unroll
        for (int ni = 0; ni < 4; ni++) {
            float4 gv = *(const float4*)(gr + ni * 16 + q * 4);
            float e0 = acc1[ni][0] * (lam * gv.x + oml);
            float e1 = acc1[ni][1] * (lam * gv.y + oml);
            float e2 = acc1[ni][2] * (lam * gv.z + oml);
            float e3 = acc1[ni][3] * (lam * gv.w + oml);
            uint2 pk;
            pk.x = (unsigned int)f2bf(e0) | ((unsigned int)f2bf(e1) << 16);
            pk.y = (unsigned int)f2bf(e2) | ((unsigned int)f2bf(e3) << 16);
            *(uint2*)&xtl[og * 72 + ni * 16 + q * 4] = pk;
        }
        // GEMM2: a2 row = og (same-wave RAW on xtl), b2 from swizzled w2s LDS
        #pragma unroll
        for (int ks2 = 0; ks2 < 2; ks2++) {
            bf16x8 a2 = *(const bf16x8*)&xtl[og * 72 + ks2 * 32 + q * 8];
            #pragma unroll
            for (int ni = 0; ni < 4; ni++) {
                int s = ni * 16 + rr;
                bf16x8 b2 = *(const bf16x8*)&w2s[cur][s * 64 + (((ks2 * 4 + q) ^ (s & 7)) << 3)];
                acc2[ni] = __builtin_amdgcn_mfma_f32_16x16x32_bf16(a2, b2, acc2[ni], 0, 0, 0);
            }
        }
        __syncthreads();   // drains staged gld16 (vmcnt) + protects buffers
    }
    #pragma unroll
    for (int ni = 0; ni < 4; ni++)
        #pragma unroll
        for (int j = 0; j < 4; j++) {
            int row = rowv[j];
            if (row < D1_OUT) {
                int col = ni * 16 + rr;
                float v = acc2[ni][j] + Bias[row * D2_OUT + col];
                out[((size_t)b * D1_OUT + row) * D2_OUT + col] = fmaxf(v, 0.f);
            }
        }
}

extern "C" void kernel_launch(void* const* d_in, const int* in_sizes, int n_in,
                              void* d_out, int out_size, void* d_ws, size_t ws_size,
                              hipStream_t stream) {
    const float* x    = (const float*)d_in[0];
    const float* W1   = (const float*)d_in[1];
    const float* W    = (const float*)d_in[2];
    const float* W2   = (const float*)d_in[3];
    const float* Bias = (const float*)d_in[4];
    const float* lam  = (const float*)d_in[5];
    float* out = (float*)d_out;
    float* A   = out + OUT0_SZ;                    // second output region

    char* ws = (char*)d_ws;
    // region 0 (64 MB): E (first 40 MB) then reused as xbT after softmax
    unsigned short* E   = (unsigned short*)(ws);
    unsigned short* xbT = (unsigned short*)(ws);
    unsigned short* wt  = (unsigned short*)(ws + 67108864);   // 2 MB
    unsigned short* w2g = (unsigned short*)(ws + 69206016);   // 128 KB (swizzled chunk-major)
    unsigned short* w1p = (unsigned short*)(ws + 69337088);   // 16 KB  (total ~69.4 MB)

    hipLaunchKernelGGL(k_prep_small, dim3(73), dim3(256), 0, stream, W1, W, W2, w2g, w1p);
    hipLaunchKernelGGL(k_transpose_w, dim3(32, 32), dim3(256), 0, stream, W, wt);
    hipLaunchKernelGGL(k_gemm1, dim3(1280), dim3(256), 0, stream, x, wt, E);
    hipLaunchKernelGGL(k_softmax, dim3(5120), dim3(256), 0, stream, E, A);
    hipLaunchKernelGGL(k_prepxT, dim3(8192), dim3(256), 0, stream, x, xbT);
    hipLaunchKernelGGL(k_fused, dim3(512), dim3(512), 0, stream, xbT, w1p, A, w2g, Bias, lam, out);
}

// Round 6
// 135.248 us; speedup vs baseline: 1.4814x; 1.0649x over previous
//
#include <hip/hip_runtime.h>
#include <cstdint>
#include <cstddef>

typedef __attribute__((ext_vector_type(8))) short bf16x8;
typedef __attribute__((ext_vector_type(4))) float f32x4;
typedef __attribute__((ext_vector_type(8))) unsigned short ushort8;
typedef __attribute__((ext_vector_type(4))) unsigned short ushort4v;

#define B_SZ   512
#define D1_IN  40
#define T_DIM  1024
#define D1_OUT 120
#define D2_OUT 64
#define OUT0_SZ (B_SZ * D1_OUT * D2_OUT) // 3932160

// per-bn bitmask of nonzero 32-wide k-steps of W (general sparsity skip)
__device__ unsigned int g_wmask[8];

// ---- helpers ----
__device__ __forceinline__ unsigned short f2bf(float f) {
    unsigned int u = __float_as_uint(f);
    u += 0x7FFFu + ((u >> 16) & 1u);   // RNE
    return (unsigned short)(u >> 16);
}
__device__ __forceinline__ void gld16v(const void* g, void* l) {
    __builtin_amdgcn_global_load_lds(
        (const __attribute__((address_space(1))) unsigned int*)g,
        (__attribute__((address_space(3))) unsigned int*)l, 16, 0, 0);
}

// ---- merged small prep: W2 swizzled re-layout (blocks 0..63), wmask (64..71), w1pad (72) ----
// w2g layout: [tc][s][blk ^ (s&7)][8]  (chunk-major so a 64-t chunk is one contiguous 8KB)
__global__ __launch_bounds__(256) void k_prep_small(const float* __restrict__ W1,
                                                    const float* __restrict__ W,
                                                    const float* __restrict__ W2,
                                                    unsigned short* __restrict__ w2g,
                                                    unsigned short* __restrict__ w1p) {
    int blk = blockIdx.x, tid = threadIdx.x;
    if (blk < 64) {
        __shared__ float tile[32][33];
        int c0 = (blk & 1) * 32, r0 = (blk >> 1) * 32;
        int tx = tid & 31, ty = tid >> 5;
        #pragma unroll
        for (int i = 0; i < 4; i++)
            tile[ty + i * 8][tx] = W2[(size_t)(r0 + ty + i * 8) * D2_OUT + c0 + tx];
        __syncthreads();
        #pragma unroll
        for (int i = 0; i < 4; i++) {
            int s = c0 + ty + i * 8;      // 0..63
            int t = r0 + tx;              // 0..1023
            size_t idx = ((size_t)(t >> 6) * 64 + s) * 64
                       + ((((t >> 3) & 7) ^ (s & 7)) << 3) + (t & 7);
            w2g[idx] = f2bf(tile[tx][ty + i * 8]);
        }
    } else if (blk < 72) {
        __shared__ unsigned int sm[256];
        int bn = blk - 64;
        int rbase = tid >> 5, c0 = (tid & 31) * 4;
        unsigned int m = 0;
        for (int ks = 0; ks < 32; ks++) {
            bool nz = false;
            #pragma unroll
            for (int i = 0; i < 4; i++) {
                int r = ks * 32 + rbase + i * 8;
                float4 v = *(const float4*)(W + (size_t)r * T_DIM + bn * 128 + c0);
                nz |= (v.x != 0.f) | (v.y != 0.f) | (v.z != 0.f) | (v.w != 0.f);
            }
            if (nz) m |= (1u << ks);
        }
        sm[tid] = m;
        __syncthreads();
        if (tid == 0) {
            unsigned int acc = 0;
            for (int i = 0; i < 256; i++) acc |= sm[i];
            g_wmask[bn] = acc;
        }
    } else {
        for (int i = tid; i < 128 * 64; i += 256) {
            int o = i >> 6, f = i & 63;
            w1p[i] = (o < D1_OUT && f < D1_IN) ? f2bf(W1[o * D1_IN + f]) : (unsigned short)0;
        }
    }
}

// ---- transpose W (1024x1024 fp32) -> wt (1024x1024 bf16) ----
__global__ __launch_bounds__(256) void k_transpose_w(const float* __restrict__ src,
                                                     unsigned short* __restrict__ dst) {
    __shared__ float tile[32][33];
    int c0 = blockIdx.x * 32, r0 = blockIdx.y * 32;
    int tx = threadIdx.x & 31, ty = threadIdx.x >> 5;
    #pragma unroll
    for (int i = 0; i < 4; i++)
        tile[ty + i * 8][tx] = src[(size_t)(r0 + ty + i * 8) * T_DIM + c0 + tx];
    __syncthreads();
    #pragma unroll
    for (int i = 0; i < 4; i++)
        dst[(size_t)(c0 + ty + i * 8) * T_DIM + r0 + tx] = f2bf(tile[tx][ty + i * 8]);
}

// ---- GEMM1 + softmax fused: A = softmax(x @ W, axis=1) written directly (fp32).
//      Block = 32 E-rows x 1024 cols. 8 waves; wave w owns panel bn=w with its own
//      k-step mask -> barrier-free K loop, frags loaded straight to registers. ----
__global__ __launch_bounds__(512) void k_gemm1sm(const float* __restrict__ x,
                                                 const unsigned short* __restrict__ wt,
                                                 float* __restrict__ A) {
    __shared__ float red[32][9];
    int row0 = blockIdx.x * 32;
    int tid = threadIdx.x, l = tid & 63, w = tid >> 6;
    int rr = l & 15, q = l >> 4;
    unsigned int mask = g_wmask[w];
    f32x4 acc[2][8] = {};
    const unsigned short* wtb = wt + (size_t)(w * 128) * T_DIM;
    for (int ks = 0; ks < 32; ks++) {
        if (!((mask >> ks) & 1u)) continue;
        int k0 = ks * 32;
        bf16x8 a[2];
        #pragma unroll
        for (int m = 0; m < 2; m++) {
            const float* xp = x + (size_t)(row0 + m * 16 + rr) * T_DIM + k0 + q * 8;
            float4 v0 = *(const float4*)xp;
            float4 v1 = *(const float4*)(xp + 4);
            bf16x8 t;
            t[0] = (short)f2bf(v0.x); t[1] = (short)f2bf(v0.y);
            t[2] = (short)f2bf(v0.z); t[3] = (short)f2bf(v0.w);
            t[4] = (short)f2bf(v1.x); t[5] = (short)f2bf(v1.y);
            t[6] = (short)f2bf(v1.z); t[7] = (short)f2bf(v1.w);
            a[m] = t;
        }
        #pragma unroll
        for (int n = 0; n < 8; n++) {
            bf16x8 b = *(const bf16x8*)(wtb + (size_t)(n * 16 + rr) * T_DIM + k0 + q * 8);
            #pragma unroll
            for (int m = 0; m < 2; m++)
                acc[m][n] = __builtin_amdgcn_mfma_f32_16x16x32_bf16(a[m], b, acc[m][n], 0, 0, 0);
        }
    }
    // ---- softmax over the full 1024 cols (fp32 accs) ----
    float rmax[2][4];
    #pragma unroll
    for (int m = 0; m < 2; m++)
        #pragma unroll
        for (int jj = 0; jj < 4; jj++) {
            float mx = acc[m][0][jj];
            #pragma unroll
            for (int n = 1; n < 8; n++) mx = fmaxf(mx, acc[m][n][jj]);
            #pragma unroll
            for (int off = 1; off < 16; off <<= 1) mx = fmaxf(mx, __shfl_xor(mx, off));
            rmax[m][jj] = mx;
        }
    if (rr == 0) {
        #pragma unroll
        for (int m = 0; m < 2; m++)
            #pragma unroll
            for (int jj = 0; jj < 4; jj++)
                red[m * 16 + q * 4 + jj][w] = rmax[m][jj];
    }
    __syncthreads();
    float gmax[2][4];
    #pragma unroll
    for (int m = 0; m < 2; m++)
        #pragma unroll
        for (int jj = 0; jj < 4; jj++) {
            float g = red[m * 16 + q * 4 + jj][0];
            #pragma unroll
            for (int ww = 1; ww < 8; ww++) g = fmaxf(g, red[m * 16 + q * 4 + jj][ww]);
            gmax[m][jj] = g;
        }
    __syncthreads();   // all gmax reads done before red is reused
    float rsum[2][4];
    #pragma unroll
    for (int m = 0; m < 2; m++)
        #pragma unroll
        for (int jj = 0; jj < 4; jj++) {
            float s = 0.f;
            #pragma unroll
            for (int n = 0; n < 8; n++) {
                float p = __expf(acc[m][n][jj] - gmax[m][jj]);
                acc[m][n][jj] = p;
                s += p;
            }
            #pragma unroll
            for (int off = 1; off < 16; off <<= 1) s += __shfl_xor(s, off);
            rsum[m][jj] = s;
        }
    if (rr == 0) {
        #pragma unroll
        for (int m = 0; m < 2; m++)
            #pragma unroll
            for (int jj = 0; jj < 4; jj++)
                red[m * 16 + q * 4 + jj][w] = rsum[m][jj];
    }
    __syncthreads();
    #pragma unroll
    for (int m = 0; m < 2; m++)
        #pragma unroll
        for (int jj = 0; jj < 4; jj++) {
            float s = red[m * 16 + q * 4 + jj][0];
            #pragma unroll
            for (int ww = 1; ww < 8; ww++) s += red[m * 16 + q * 4 + jj][ww];
            float inv = 1.f / s;
            size_t rowg = (size_t)(row0 + m * 16 + q * 4 + jj) * T_DIM + w * 128;
            #pragma unroll
            for (int n = 0; n < 8; n++)
                A[rowg + n * 16 + rr] = acc[m][n][jj] * inv;
        }
}

// ---- fused: X_bar^T = x^T@W1^T via MFMA (D=[t][o]), gate from LDS, X_tilde->LDS b64,
//      out = X_tilde@W2 + B, relu. x staged fp32 directly (granule-swizzled gld16),
//      converted to bf16 at fragment build; f>=40 slots multiply w1p zeros. ----
__global__ __launch_bounds__(512) void k_fused(const float* __restrict__ x,
                                               const unsigned short* __restrict__ w1p,
                                               const float* __restrict__ A,
                                               const unsigned short* __restrict__ w2g,
                                               const float* __restrict__ Bias,
                                               const float* __restrict__ lamp,
                                               float* __restrict__ out) {
    __shared__ float xfst[2][40 * 64];          // x chunk [f][t], granule-swizzled  20KB
    __shared__ unsigned short w2s[2][64 * 64];  // swizzled w2 chunk                 16KB
    __shared__ float gst[2][40 * 64];           // A chunk [f][t] fp32               20KB
    __shared__ unsigned short xtl[128 * 72];    // X_tilde [o][t], stride 72         18KB
    int b = blockIdx.x;
    int tid = threadIdx.x, l = tid & 63, w = tid >> 6;   // 8 waves
    int rr = l & 15, q = l >> 4;
    float lam = fminf(fmaxf(lamp[0], 0.f), 1.f), oml = 1.f - lam;
    bf16x8 aw[2];
    #pragma unroll
    for (int ks = 0; ks < 2; ks++)
        aw[ks] = *(const bf16x8*)(w1p + (w * 16 + rr) * 64 + ks * 32 + q * 8);
    int og = w * 16 + rr;              // lane's fixed o (strip row)
    int am = og % D1_IN;               // gate row of A
    int rowv[4];
    #pragma unroll
    for (int j = 0; j < 4; j++) rowv[j] = w * 16 + q * 4 + j;
    f32x4 acc2[4] = {};
    const float* xb = x + (size_t)b * D1_IN * T_DIM;
    const float* Ab = A + (size_t)b * D1_IN * T_DIM;

    // stage chunk tc into buffer buf (all coalesced global_load_lds)
    auto STAGE = [&](int buf, int tc) {
        int t0 = tc * 64;
        // x rows fp32, granule-swizzled source (g ^= ((f>>3)&3)<<1), linear dest
        {
            int f = w * 4 + (l >> 4), g = l & 15;
            int sw = ((f >> 3) & 3) << 1;
            gld16v(xb + (size_t)f * T_DIM + t0 + ((g ^ sw) << 2), &xfst[buf][w * 256]);
            if (w < 2) {
                int f2 = 32 + w * 4 + (l >> 4);
                gld16v(xb + (size_t)f2 * T_DIM + t0 + ((g ^ 0) << 2),   // swz(32..39)=0
                       &xfst[buf][(32 + w * 4) * 64]);
            }
        }
        // w2 chunk: contiguous 1KB per wave (chunk-major global layout)
        gld16v(w2g + (size_t)tc * 4096 + w * 512 + l * 8, &w2s[buf][w * 512]);
        // gate: A rows fp32
        gld16v(Ab + (size_t)(w * 4 + (l >> 4)) * T_DIM + t0 + (l & 15) * 4,
               &gst[buf][w * 256]);
        if (w < 2)
            gld16v(Ab + (size_t)(32 + w * 4 + (l >> 4)) * T_DIM + t0 + (l & 15) * 4,
                   &gst[buf][(32 + w * 4) * 64]);
    };

    STAGE(0, 0);
    __syncthreads();
    for (int tc = 0; tc < 16; tc++) {
        int cur = tc & 1;
        if (tc < 15) STAGE(cur ^ 1, tc + 1);
        // X_bar^T via MFMA: build A-op frags from fp32 LDS (cvt to bf16)
        f32x4 acc1[4] = {};
        #pragma unroll
        for (int ni = 0; ni < 4; ni++) {
            int tq = ni * 4 + (rr >> 2), tr = rr & 3;
            #pragma unroll
            for (int ks = 0; ks < 2; ks++) {
                int sw = ks ? 0 : (q << 1);
                int toff = (((tq ^ sw)) << 2) + tr;
                bf16x8 bx;
                #pragma unroll
                for (int j = 0; j < 8; j++) {
                    int fe = ks ? (q == 0 ? 32 + j : j) : (q * 8 + j);
                    bx[j] = (short)f2bf(xfst[cur][fe * 64 + toff]);
                }
                acc1[ni] = __builtin_amdgcn_mfma_f32_16x16x32_bf16(bx, aw[ks], acc1[ni], 0, 0, 0);
            }
        }
        // gate (LDS, lane-fixed row am) + pack -> one ds_write_b64 per ni
        const float* gr = &gst[cur][am * 64];
        #pragma unroll
        for (int ni = 0; ni < 4; ni++) {
            float4 gv = *(const float4*)(gr + ni * 16 + q * 4);
            float e0 = acc1[ni][0] * (lam * gv.x + oml);
            float e1 = acc1[ni][1] * (lam * gv.y + oml);
            float e2 = acc1[ni][2] * (lam * gv.z + oml);
            float e3 = acc1[ni][3] * (lam * gv.w + oml);
            uint2 pk;
            pk.x = (unsigned int)f2bf(e0) | ((unsigned int)f2bf(e1) << 16);
            pk.y = (unsigned int)f2bf(e2) | ((unsigned int)f2bf(e3) << 16);
            *(uint2*)&xtl[og * 72 + ni * 16 + q * 4] = pk;
        }
        // GEMM2: a2 row = og (same-wave RAW on xtl), b2 from swizzled w2s LDS
        #pragma unroll
        for (int ks2 = 0; ks2 < 2; ks2++) {
            bf16x8 a2 = *(const bf16x8*)&xtl[og * 72 + ks2 * 32 + q * 8];
            #pragma unroll
            for (int ni = 0; ni < 4; ni++) {
                int s = ni * 16 + rr;
                bf16x8 b2 = *(const bf16x8*)&w2s[cur][s * 64 + (((ks2 * 4 + q) ^ (s & 7)) << 3)];
                acc2[ni] = __builtin_amdgcn_mfma_f32_16x16x32_bf16(a2, b2, acc2[ni], 0, 0, 0);
            }
        }
        __syncthreads();   // drains staged gld16 (vmcnt) + protects buffers
    }
    #pragma unroll
    for (int ni = 0; ni < 4; ni++)
        #pragma unroll
        for (int j = 0; j < 4; j++) {
            int row = rowv[j];
            if (row < D1_OUT) {
                int col = ni * 16 + rr;
                float v = acc2[ni][j] + Bias[row * D2_OUT + col];
                out[((size_t)b * D1_OUT + row) * D2_OUT + col] = fmaxf(v, 0.f);
            }
        }
}

extern "C" void kernel_launch(void* const* d_in, const int* in_sizes, int n_in,
                              void* d_out, int out_size, void* d_ws, size_t ws_size,
                              hipStream_t stream) {
    const float* x    = (const float*)d_in[0];
    const float* W1   = (const float*)d_in[1];
    const float* W    = (const float*)d_in[2];
    const float* W2   = (const float*)d_in[3];
    const float* Bias = (const float*)d_in[4];
    const float* lam  = (const float*)d_in[5];
    float* out = (float*)d_out;
    float* A   = out + OUT0_SZ;                    // second output region

    char* ws = (char*)d_ws;
    unsigned short* wt  = (unsigned short*)(ws);              // 2 MB
    unsigned short* w2g = (unsigned short*)(ws + 2097152);    // 128 KB
    unsigned short* w1p = (unsigned short*)(ws + 2228224);    // 16 KB (total ~2.25 MB)

    hipLaunchKernelGGL(k_prep_small, dim3(73), dim3(256), 0, stream, W1, W, W2, w2g, w1p);
    hipLaunchKernelGGL(k_transpose_w, dim3(32, 32), dim3(256), 0, stream, W, wt);
    hipLaunchKernelGGL(k_gemm1sm, dim3(640), dim3(512), 0, stream, x, wt, A);
    hipLaunchKernelGGL(k_fused, dim3(512), dim3(512), 0, stream, x, w1p, A, w2g, Bias, lam, out);
}